// Round 2
// baseline (2011.296 us; speedup 1.0000x reference)
//
#include <hip/hip_runtime.h>
#include <hip/hip_fp16.h>
#include <hip/hip_cooperative_groups.h>

namespace cg = cooperative_groups;

// ---------------- problem constants ----------------
constexpr int B_ = 256;        // batch
constexpr int K_ = 6144;       // block length
constexpr int NITER = 6;
constexpr int L_ = 6;          // window valid length -> C_=1024 chunks
constexpr int W0_ = 6;         // uniform-init warmup (iteration 0)
constexpr int C_ = K_ / L_;    // chunks = 1024
constexpr float LOG2E = 1.4426950408889634f;
constexpr float LN2   = 0.6931471805599453f;

static_assert(K_ % L_ == 0, "");
static_assert((L_ % 2) == 0 && (W0_ % 2) == 0, "");
static_assert(W0_ <= L_, "uniform-warmup trick requires W0 <= L");
static_assert(K_ % C_ == 0, "");

#if __has_builtin(__builtin_amdgcn_exp2f)
#define EXP2F(x) __builtin_amdgcn_exp2f(x)
#else
#define EXP2F(x) exp2f(x)
#endif
#if __has_builtin(__builtin_amdgcn_logf)
#define LOG2F(x) __builtin_amdgcn_logf(x)
#else
#define LOG2F(x) log2f(x)
#endif
#if __has_builtin(__builtin_amdgcn_rcpf)
#define RCPF(x) __builtin_amdgcn_rcpf(x)
#else
#define RCPF(x) (1.0f / (x))
#endif

// ---- bf16 scalar helpers (RNE) ----
__device__ __forceinline__ float b2f(unsigned short u) {
  return __uint_as_float((unsigned)u << 16);
}
__device__ __forceinline__ unsigned short f2b(float f) {
  unsigned u = __float_as_uint(f);
  u += 0x7FFFu + ((u >> 16) & 1u);
  return (unsigned short)(u >> 16);
}

// trellis: fb(s,u)=u^s1^s0, nxt(s,u)=(fb<<2)|(s>>1), par(s,u)=u^s1^s2
__device__ __forceinline__ void gam_lin(float gxv, float gyv, float g[4]) {
  float es = EXP2F(-fabsf(gxv));
  float ep = EXP2F(-fabsf(gyv));
  float fu0 = gxv >= 0.0f ? 1.0f : es;
  float fu1 = gxv >= 0.0f ? es : 1.0f;
  float fp0 = gyv >= 0.0f ? 1.0f : ep;
  float fp1 = gyv >= 0.0f ? ep : 1.0f;
  g[0] = fu0 * fp0; g[1] = fu0 * fp1;
  g[2] = fu1 * fp0; g[3] = fu1 * fp1;
}

__device__ __forceinline__ void step_fwd_lin(float a[8], const float g[4]) {
  float an[8];
#pragma unroll
  for (int sn = 0; sn < 8; ++sn) {
    const int u0 = ((sn >> 2) ^ (sn & 1)) & 1;
    const int p0 = ((sn >> 2) ^ ((sn >> 1) & 1)) & 1;
    an[sn] = a[(sn & 3) * 2] * g[u0 * 2 + p0]
           + a[(sn & 3) * 2 + 1] * g[(u0 ^ 1) * 2 + (p0 ^ 1)];
  }
#pragma unroll
  for (int s = 0; s < 8; ++s) a[s] = an[s];
}

__device__ __forceinline__ void step_bwd_lin(float bt[8], const float g[4]) {
  float bn[8];
#pragma unroll
  for (int s = 0; s < 8; ++s) {
    const int s0 = s & 1, s1b = (s >> 1) & 1, s2b = (s >> 2) & 1;
    const int f0 = s1b ^ s0, q = s1b ^ s2b;
    bn[s] = g[q] * bt[(f0 << 2) | (s >> 1)]
          + g[2 + (q ^ 1)] * bt[((f0 ^ 1) << 2) | (s >> 1)];
  }
#pragma unroll
  for (int s = 0; s < 8; ++s) bt[s] = bn[s];
}

// max-renorm with tiny floor injection: NaN/underflow-proof
__device__ __forceinline__ void renorm_lin(float a[8]) {
  float m = fmaxf(fmaxf(fmaxf(a[0], a[1]), fmaxf(a[2], a[3])),
                  fmaxf(fmaxf(a[4], a[5]), fmaxf(a[6], a[7])));
  float r = RCPF(fmaxf(m, 1e-30f));
#pragma unroll
  for (int s = 0; s < 8; ++s) a[s] = fmaf(a[s], r, 1e-32f);
}

// ---- log8-packed boundary states: u8 = round(-16*log2(x)), clamp 255. ----
__device__ __forceinline__ void store8_log8(unsigned char* p, const float a[8]) {
  unsigned int us[8];
#pragma unroll
  for (int s = 0; s < 8; ++s) {
    float l = -16.0f * LOG2F(a[s]);
    l = fminf(l, 255.0f);
    us[s] = (unsigned int)(l + 0.5f);
  }
  uint2 v;
  v.x = us[0] | (us[1] << 8) | (us[2] << 16) | (us[3] << 24);
  v.y = us[4] | (us[5] << 8) | (us[6] << 16) | (us[7] << 24);
  *(uint2*)p = v;
}

__device__ __forceinline__ void unpack8_log8(uint2 v, float a[8]) {
#pragma unroll
  for (int s = 0; s < 4; ++s)
    a[s] = EXP2F(-0.0625f * (float)((v.x >> (8 * s)) & 0xFFu));
#pragma unroll
  for (int s = 0; s < 4; ++s)
    a[4 + s] = EXP2F(-0.0625f * (float)((v.y >> (8 * s)) & 0xFFu));
}

// ---------------- workspace layout (shared host/device) -------------------
struct WSL {
  float* lpostT;
  __half* gx1; __half* gx2;
  unsigned short* gy1; unsigned short* gy2;
  __half* ls1; __half* ls2;
  int* inv;
  unsigned char* S1a; unsigned char* S1b;
  unsigned char* T1a; unsigned char* T1b;
  unsigned char* S2a; unsigned char* S2b;
  unsigned char* T2a; unsigned char* T2b;
};

__host__ __device__ inline WSL ws_layout(char* ws) {
  const size_t KB = (size_t)K_ * B_;
  const size_t PB = KB * 4;
  const size_t PH = KB * 2;
  WSL w;
  w.lpostT = (float*)(ws);
  w.gx1 = (__half*)(ws + PB);
  w.gx2 = (__half*)(ws + PB + PH);
  w.gy1 = (unsigned short*)(ws + PB + PH * 2);
  w.gy2 = (unsigned short*)(ws + PB + PH * 3);
  w.ls1 = (__half*)(ws + PB + PH * 4);
  w.ls2 = (__half*)(ws + PB + PH * 5);
  w.inv = (int*)(ws + PB + PH * 6);
  const size_t SB = (size_t)(C_ + 1) * B_ * 8;
  char* nb = ws + PB + PH * 6 + 65536;
  w.S1a = (unsigned char*)(nb);          w.S1b = (unsigned char*)(nb + SB);
  w.T1a = (unsigned char*)(nb + SB * 2); w.T1b = (unsigned char*)(nb + SB * 3);
  w.S2a = (unsigned char*)(nb + SB * 4); w.S2b = (unsigned char*)(nb + SB * 5);
  w.T2a = (unsigned char*)(nb + SB * 6); w.T2b = (unsigned char*)(nb + SB * 7);
  return w;
}

// ---------------- one windowed BCJR half-iteration (linear domain) --------
// Bit-identical to the proven k_half kernel; chunk index is a parameter so
// both the persistent megakernel (grid-stride) and the fallback launcher
// can call it.
__device__ void half_body(const int c,
                          const __half* __restrict__ gx,
                          const unsigned short* __restrict__ gy,
                          const __half* __restrict__ lsloc,
                          const int* __restrict__ map,
                          __half* __restrict__ gxother,
                          float* __restrict__ lpost_out,
                          const unsigned char* __restrict__ Sread,
                          unsigned char* __restrict__ Swrite,
                          const unsigned char* __restrict__ Tread,
                          unsigned char* __restrict__ Twrite,
                          int wmode, int mode, int wrS) {
  const int b = threadIdx.x;
  const int kv = c * L_;
  const int kend = kv + L_;

  // ---- issue ALL independent loads upfront ----
  __half hgx[L_];
  unsigned short rgy[L_];
  __half hls[L_];
#pragma unroll
  for (int i = 0; i < L_; ++i) {
    size_t o = (size_t)(kv + i) * B_ + b;
    hgx[i] = gx[o];
    rgy[i] = gy[o];
  }
  if (mode == 0) {
#pragma unroll
    for (int i = 0; i < L_; ++i)
      hls[i] = lsloc[(size_t)(kv + i) * B_ + b];   // local rows, coalesced
  }
  int jmap[L_];
#pragma unroll
  for (int i = 0; i < L_; ++i) jmap[i] = map[kv + i];     // block-uniform
  uint2 sraw, traw;
  __half wfx[W0_], wbx[W0_];
  unsigned short wfy[W0_], wby[W0_];
  if (wmode == 2) {
    if (c > 0)
      sraw = *(const uint2*)&Sread[((size_t)c * B_ + b) * 8];
    if (c < C_ - 1)
      traw = *(const uint2*)&Tread[((size_t)(c + 1) * B_ + b) * 8];
  } else {
    // warmup gammas, all upfront (wu == W0_ exactly, since kv >= W0_ at c>=1)
    if (c > 0) {
#pragma unroll
      for (int q = 0; q < W0_; ++q) {
        size_t o = (size_t)(kv - W0_ + q) * B_ + b;
        wfx[q] = gx[o]; wfy[q] = gy[o];
      }
    }
    if (c < C_ - 1) {
#pragma unroll
      for (int q = 0; q < W0_; ++q) {
        size_t o = (size_t)(kend + W0_ - 1 - q) * B_ + b;
        wbx[q] = gx[o]; wby[q] = gy[o];
      }
    }
  }

  // ---- convert valid gamma (gvx kept: needed for extrinsic) ----
  float gvx[L_];
  float gc[L_][4];
#pragma unroll
  for (int i = 0; i < L_; ++i) {
    gvx[i] = __half2float(hgx[i]);
    gam_lin(gvx[i], b2f(rgy[i]), gc[i]);
  }

  // ---------------- forward ----------------
  float a[8];
  if (c == 0) {
    a[0] = 1.0f;
#pragma unroll
    for (int s = 1; s < 8; ++s) a[s] = 0.0f;
  } else if (wmode == 0) {
    if (c == 1) {                    // warmup starts at position 0: exact init
      a[0] = 1.0f;
#pragma unroll
      for (int s = 1; s < 8; ++s) a[s] = 0.0f;
    } else {
#pragma unroll
      for (int s = 0; s < 8; ++s) a[s] = 1.0f;
    }
#pragma unroll
    for (int q = 0; q < W0_; ++q) {
      float g[4];
      gam_lin(__half2float(wfx[q]), b2f(wfy[q]), g);
      step_fwd_lin(a, g);
      if (q & 1) renorm_lin(a);
    }
  } else {
    unpack8_log8(sraw, a);           // pure inheritance (c>0 here)
  }
  // valid region: record alpha, then step (all L steps -> a = alpha(kend))
  float a2d[L_][8];
#pragma unroll
  for (int i = 0; i < L_; ++i) {
#pragma unroll
    for (int s = 0; s < 8; ++s) a2d[i][s] = a[s];
    step_fwd_lin(a, gc[i]);
    if (i & 1) renorm_lin(a);
  }
  if (wrS)
    store8_log8(&Swrite[((size_t)(c + 1) * B_ + b) * 8], a);

  // ---------------- backward + posterior ----------------
  float bt[8];
  if (c == C_ - 1) {
#pragma unroll
    for (int s = 0; s < 8; ++s) bt[s] = 1.0f;    // exact tail init (uniform)
  } else if (wmode == 0) {
#pragma unroll
    for (int s = 0; s < 8; ++s) bt[s] = 1.0f;    // uniform (exact at c=C_-2)
#pragma unroll
    for (int q = 0; q < W0_; ++q) {
      float g[4];
      gam_lin(__half2float(wbx[q]), b2f(wby[q]), g);
      step_bwd_lin(bt, g);
      if (q & 1) renorm_lin(bt);
    }
  } else {
    unpack8_log8(traw, bt);          // pure inheritance (c<C_-1 here)
  }
  // valid region, descending: posterior + extrinsic + beta step
#pragma unroll
  for (int ii = 0; ii < L_; ++ii) {
    const int i = L_ - 1 - ii;
    const float* g = gc[i];
    float s00 = 0.0f, s01 = 0.0f, s10 = 0.0f, s11 = 0.0f;
    float bn[8];
#pragma unroll
    for (int s = 0; s < 8; ++s) {
      const int s0 = s & 1, s1b = (s >> 1) & 1, s2b = (s >> 2) & 1;
      const int f0 = s1b ^ s0, q = s1b ^ s2b;
      float b0 = bt[(f0 << 2) | (s >> 1)];
      float b1 = bt[((f0 ^ 1) << 2) | (s >> 1)];
      float m0 = a2d[i][s] * b0;
      float m1 = a2d[i][s] * b1;
      if (q == 0) { s00 += m0; s10 += m1; } else { s01 += m0; s11 += m1; }
      bn[s] = g[q] * b0 + g[2 + (q ^ 1)] * b1;
    }
    float t0 = g[0] * s00 + g[1] * s01;
    float t1 = g[3] * s10 + g[2] * s11;
    float lpost = LOG2F(fmaxf(t0, 1e-37f)) - LOG2F(fmaxf(t1, 1e-37f));
    const size_t oo = (size_t)jmap[i] * B_ + b;
    if (mode == 0) {
      float le = lpost - gvx[i];               // lpost - (ls + la)
      gxother[oo] = __float2half(__half2float(hls[i]) + le);
    } else {
      lpost_out[oo] = -LN2 * lpost;            // final output value, row perm[kk]
    }
#pragma unroll
    for (int s = 0; s < 8; ++s) bt[s] = bn[s];
    if (ii & 1) renorm_lin(bt);
  }
  if (wrS)
    store8_log8(&Twrite[((size_t)c * B_ + b) * 8], bt);
}

// grid barrier with explicit agent-scope fences (belt-and-braces for
// cross-XCD L2 visibility: release writeback before arrival, acquire
// invalidate after departure).
__device__ __forceinline__ void gbar(cg::grid_group& g) {
  __threadfence();
  g.sync();
  __threadfence();
}

// ---------------- persistent cooperative megakernel -----------------------
// Grid-size-agnostic: every phase is a grid-stride loop, so the host can
// launch whatever cooperative grid the runtime admits (queried via the
// occupancy API). At grid==C_=1024 each loop runs exactly once per block.
__global__ __launch_bounds__(256, 4) void k_fused(const int* __restrict__ perm,
                                                  float* __restrict__ out,
                                                  char* __restrict__ ws) {
  WSL w = ws_layout(ws);
  const int tid = threadIdx.x;
  cg::grid_group grid = cg::this_grid();
  __shared__ float t[64][65];

  // ---- phase P: prep2 (ls2 permuted copy + inverse permutation) ----
  for (int c = blockIdx.x; c < C_; c += gridDim.x) {
    constexpr int RPB = K_ / C_;   // 6 rows per chunk-slot
#pragma unroll
    for (int r = 0; r < RPB; ++r) {
      const int j = c * RPB + r;
      const int p = perm[j];
      w.ls2[(size_t)j * B_ + tid] = w.ls1[(size_t)p * B_ + tid];
      if (tid == 0) w.inv[p] = j;
    }
  }
  gbar(grid);

  // ---- 12 serial BCJR half-iterations ----
  for (int it = 0; it < NITER; ++it) {
    const int pr = it & 1;
    const int wm = (it == 0) ? 0 : 2;
    const int wrS = (it != NITER - 1) ? 1 : 0;
    unsigned char* S1r = pr ? w.S1b : w.S1a;
    unsigned char* S1w = pr ? w.S1a : w.S1b;
    unsigned char* T1r = pr ? w.T1b : w.T1a;
    unsigned char* T1w = pr ? w.T1a : w.T1b;
    unsigned char* S2r = pr ? w.S2b : w.S2a;
    unsigned char* S2w = pr ? w.S2a : w.S2b;
    unsigned char* T2r = pr ? w.T2b : w.T2a;
    unsigned char* T2w = pr ? w.T2a : w.T2b;
    // phase 0 (decoder 1): extrinsic -> gx2[inv[kk]]; local ls plane = ls1.
    // At it0, gx1 is uninitialized but bit-equal to ls1 (la=0): pass ls1.
    const __half* g1 = (it == 0) ? w.ls1 : w.gx1;
    for (int c = blockIdx.x; c < C_; c += gridDim.x)
      half_body(c, g1, w.gy1, w.ls1, w.inv, w.gx2, w.lpostT,
                S1r, S1w, T1r, T1w, wm, 0, wrS);
    gbar(grid);
    // phase 1 (decoder 2): extrinsic -> gx1[perm[kk]]; local ls plane = ls2
    for (int c = blockIdx.x; c < C_; c += gridDim.x)
      half_body(c, w.gx2, w.gy2, w.ls2, perm, w.gx1, w.lpostT,
                S2r, S2w, T2r, T2w, wm, (it == NITER - 1) ? 1 : 0, wrS);
    gbar(grid);
  }

  // ---- phase O: out[b,i] = lpostT[i,b] (384 transpose tiles) ----
  for (int tt = blockIdx.x; tt < (K_ / 64) * (B_ / 64); tt += gridDim.x) {
    const int i0 = (tt >> 2) * 64;     // tt / (B_/64)
    const int b0 = (tt & 3) * 64;      // tt % (B_/64)
    __syncthreads();                   // protect LDS tile reuse
    const int tb = tid & 63, iq = tid >> 6;
    for (int ii = iq; ii < 64; ii += 4)
      t[ii][tb] = w.lpostT[(size_t)(i0 + ii) * B_ + (b0 + tb)];
    __syncthreads();
    const int ik = tid & 63, bq = tid >> 6;
    for (int bb = bq; bb < 64; bb += 4)
      out[(size_t)(b0 + bb) * K_ + (i0 + ik)] = t[ik][bb];
  }
}

// ---------------- fallback kernels (proven 199us path) --------------------
__global__ __launch_bounds__(256, 4) void k_half(const __half* __restrict__ gx,
                                                 const unsigned short* __restrict__ gy,
                                                 const __half* __restrict__ lsloc,
                                                 const int* __restrict__ map,
                                                 __half* __restrict__ gxother,
                                                 float* __restrict__ lpost_out,
                                                 const unsigned char* __restrict__ Sread,
                                                 unsigned char* __restrict__ Swrite,
                                                 const unsigned char* __restrict__ Tread,
                                                 unsigned char* __restrict__ Twrite,
                                                 int wmode, int mode, int wrS) {
  half_body(blockIdx.x, gx, gy, lsloc, map, gxother, lpost_out,
            Sread, Swrite, Tread, Twrite, wmode, mode, wrS);
}

__global__ __launch_bounds__(256) void k_prep2(const __half* __restrict__ ls1,
                                               const int* __restrict__ perm,
                                               __half* __restrict__ ls2,
                                               int* __restrict__ inv) {
  const int b = threadIdx.x;
#pragma unroll
  for (int r = 0; r < 8; ++r) {
    const int j = blockIdx.x * 8 + r;
    const int p = perm[j];
    ls2[(size_t)j * B_ + b] = ls1[(size_t)p * B_ + b];
    if (b == 0) inv[p] = j;
  }
}

__global__ __launch_bounds__(256) void k_out(const float* __restrict__ lpostT,
                                             float* __restrict__ out) {
  __shared__ float t[64][65];
  const int tid = threadIdx.x;
  const int i0 = blockIdx.x * 64, b0 = blockIdx.y * 64;
  const int tb = tid & 63, iq = tid >> 6;
  for (int ii = iq; ii < 64; ii += 4) {
    t[ii][tb] = lpostT[(size_t)(i0 + ii) * B_ + (b0 + tb)];
  }
  __syncthreads();
  const int ik = tid & 63, bq = tid >> 6;
  for (int bb = bq; bb < 64; bb += 4) {
    out[(size_t)(b0 + bb) * K_ + (i0 + ik)] = t[ik][bb];
  }
}

// ---------------- prep: de-interleave + transpose + scale to log2 domain --
__global__ __launch_bounds__(256) void k_prep1(const float* __restrict__ inp,
                                               __half* __restrict__ ls1,
                                               unsigned short* __restrict__ gy1,
                                               unsigned short* __restrict__ gy2) {
  __shared__ float t[3][64][65];
  const int tid = threadIdx.x;
  const int k0 = blockIdx.x * 64, b0 = blockIdx.y * 64;
  const int tk = tid & 63, tq = tid >> 6;
  for (int bb = tq; bb < 64; bb += 4) {
    size_t base = (size_t)(b0 + bb) * (3 * K_) + 3 * (size_t)(k0 + tk);
    t[0][bb][tk] = inp[base + 0];
    t[1][bb][tk] = inp[base + 1];
    t[2][bb][tk] = inp[base + 2];
  }
  __syncthreads();
  const int tb = tid & 63, kq = tid >> 6;
  for (int kk = kq; kk < 64; kk += 4) {
    size_t o = (size_t)(k0 + kk) * B_ + (b0 + tb);
    float sv = -LOG2E * t[0][tb][kk];
    float p1 = -LOG2E * t[1][tb][kk];
    float p2 = -LOG2E * t[2][tb][kk];
    ls1[o] = __float2half(sv);
    gy1[o] = f2b(p1);
    gy2[o] = f2b(p2);
  }
}

// ---------------- launch ---------------------------------------------------
static void launch_fallback(const int* perm, float* out, char* wsb,
                            hipStream_t stream) {
  WSL w = ws_layout(wsb);
  k_prep2<<<K_ / 8, 256, 0, stream>>>(w.ls1, perm, w.ls2, w.inv);
  for (int it = 0; it < NITER; ++it) {
    const int pr = it & 1;
    const int wm = (it == 0) ? 0 : 2;
    const int wrS = (it != NITER - 1) ? 1 : 0;
    unsigned char* S1r = pr ? w.S1b : w.S1a; unsigned char* S1w = pr ? w.S1a : w.S1b;
    unsigned char* T1r = pr ? w.T1b : w.T1a; unsigned char* T1w = pr ? w.T1a : w.T1b;
    unsigned char* S2r = pr ? w.S2b : w.S2a; unsigned char* S2w = pr ? w.S2a : w.S2b;
    unsigned char* T2r = pr ? w.T2b : w.T2a; unsigned char* T2w = pr ? w.T2a : w.T2b;
    const __half* g1 = (it == 0) ? w.ls1 : w.gx1;
    k_half<<<C_, 256, 0, stream>>>(g1, w.gy1, w.ls1, w.inv, w.gx2, w.lpostT,
                                   S1r, S1w, T1r, T1w, wm, 0, wrS);
    k_half<<<C_, 256, 0, stream>>>(w.gx2, w.gy2, w.ls2, perm, w.gx1, w.lpostT,
                                   S2r, S2w, T2r, T2w, wm,
                                   (it == NITER - 1) ? 1 : 0, wrS);
  }
  k_out<<<dim3(K_ / 64, B_ / 64), 256, 0, stream>>>(w.lpostT, out);
}

extern "C" void kernel_launch(void* const* d_in, const int* in_sizes, int n_in,
                              void* d_out, int out_size, void* d_ws, size_t ws_size,
                              hipStream_t stream) {
  (void)in_sizes; (void)n_in; (void)out_size; (void)ws_size;
  const float* inp = (const float*)d_in[0];
  const int* perm = (const int*)d_in[1];
  float* out = (float*)d_out;
  char* wsb = (char*)d_ws;
  WSL w = ws_layout(wsb);

  k_prep1<<<dim3(K_ / 64, B_ / 64), 256, 0, stream>>>(inp, w.ls1, w.gy1, w.gy2);

  // mode: 0 = undecided, 1 = cooperative megakernel, 2 = fallback launches.
  // Decision is made on the first non-capturing call (the harness's eager
  // correctness run precedes any graph capture), so a failing cooperative
  // launch is never issued inside a capture.
  static int g_mode = 0;
  static int g_grid = 0;

  bool launched = false;
  if (g_mode == 0) {
    hipStreamCaptureStatus cap = hipStreamCaptureStatusNone;
    (void)hipStreamIsCapturing(stream, &cap);
    if (cap == hipStreamCaptureStatusNone) {
      int nb = 0;
      if (hipOccupancyMaxActiveBlocksPerMultiprocessor(&nb, k_fused, 256, 0)
              != hipSuccess)
        nb = 0;
      int ncu = 0;
      hipDeviceProp_t prop;
      int dev = 0;
      (void)hipGetDevice(&dev);
      if (hipGetDeviceProperties(&prop, dev) == hipSuccess)
        ncu = prop.multiProcessorCount;
      long long g = (long long)nb * (long long)ncu;
      int grid = (g > C_) ? C_ : (int)g;
      if (grid >= 8) {
        void* kargs[] = {(void*)&perm, (void*)&out, (void*)&wsb};
        hipError_t e = hipLaunchCooperativeKernel(k_fused, dim3(grid),
                                                  dim3(256), kargs, 0, stream);
        if (e == hipSuccess) {
          g_mode = 1;
          g_grid = grid;
          launched = true;
        } else {
          g_mode = 2;
        }
      } else {
        g_mode = 2;
      }
    }
    // if still undecided (first call was capturing): fall back for this call
  } else if (g_mode == 1) {
    void* kargs[] = {(void*)&perm, (void*)&out, (void*)&wsb};
    (void)hipLaunchCooperativeKernel(k_fused, dim3(g_grid), dim3(256), kargs,
                                     0, stream);
    launched = true;
  }

  if (!launched)
    launch_fallback(perm, out, wsb, stream);
}

// Round 3
// 421.401 us; speedup vs baseline: 4.7729x; 4.7729x over previous
//
#include <hip/hip_runtime.h>
#include <hip/hip_fp16.h>

// ---------------- problem constants ----------------
constexpr int B_ = 256;        // batch
constexpr int K_ = 6144;       // block length
constexpr int NITER = 6;
constexpr int L_ = 6;          // window valid length -> C_=1024 chunks
constexpr int W0_ = 6;         // uniform-init warmup (iteration 0)
constexpr int C_ = K_ / L_;    // chunks = 1024
constexpr float LOG2E = 1.4426950408889634f;
constexpr float LN2   = 0.6931471805599453f;

static_assert(K_ % L_ == 0, "");
static_assert((L_ % 2) == 0 && (W0_ % 2) == 0, "");
static_assert(W0_ <= L_, "uniform-warmup trick requires W0 <= L");

#if __has_builtin(__builtin_amdgcn_exp2f)
#define EXP2F(x) __builtin_amdgcn_exp2f(x)
#else
#define EXP2F(x) exp2f(x)
#endif
#if __has_builtin(__builtin_amdgcn_logf)
#define LOG2F(x) __builtin_amdgcn_logf(x)
#else
#define LOG2F(x) log2f(x)
#endif
#if __has_builtin(__builtin_amdgcn_rcpf)
#define RCPF(x) __builtin_amdgcn_rcpf(x)
#else
#define RCPF(x) (1.0f / (x))
#endif

// ---- bf16 scalar helpers (RNE) ----
__device__ __forceinline__ float b2f(unsigned short u) {
  return __uint_as_float((unsigned)u << 16);
}
__device__ __forceinline__ unsigned short f2b(float f) {
  unsigned u = __float_as_uint(f);
  u += 0x7FFFu + ((u >> 16) & 1u);
  return (unsigned short)(u >> 16);
}

// ---- agent-scope (cross-XCD) relaxed accessors.
// On gfx950 these emit sc1-flagged global ops: stores write through past the
// (non-coherent, per-XCD) L2 to the device coherence point; loads bypass L2
// and read it. This gives targeted cross-XCD visibility with NO buffer_wbl2 /
// buffer_inv, so block-local cached planes survive across phases.
__device__ __forceinline__ float ld_dev_f32(const float* p) {
  return __hip_atomic_load(const_cast<float*>(p), __ATOMIC_RELAXED,
                           __HIP_MEMORY_SCOPE_AGENT);
}
__device__ __forceinline__ void st_dev_f32(float* p, float v) {
  __hip_atomic_store(p, v, __ATOMIC_RELAXED, __HIP_MEMORY_SCOPE_AGENT);
}
__device__ __forceinline__ unsigned long long ld_dev_u64(
    const unsigned long long* p) {
  return __hip_atomic_load(const_cast<unsigned long long*>(p),
                           __ATOMIC_RELAXED, __HIP_MEMORY_SCOPE_AGENT);
}
__device__ __forceinline__ void st_dev_u64(unsigned long long* p,
                                           unsigned long long v) {
  __hip_atomic_store(p, v, __ATOMIC_RELAXED, __HIP_MEMORY_SCOPE_AGENT);
}

// trellis: fb(s,u)=u^s1^s0, nxt(s,u)=(fb<<2)|(s>>1), par(s,u)=u^s1^s2
__device__ __forceinline__ void gam_lin(float gxv, float gyv, float g[4]) {
  float es = EXP2F(-fabsf(gxv));
  float ep = EXP2F(-fabsf(gyv));
  float fu0 = gxv >= 0.0f ? 1.0f : es;
  float fu1 = gxv >= 0.0f ? es : 1.0f;
  float fp0 = gyv >= 0.0f ? 1.0f : ep;
  float fp1 = gyv >= 0.0f ? ep : 1.0f;
  g[0] = fu0 * fp0; g[1] = fu0 * fp1;
  g[2] = fu1 * fp0; g[3] = fu1 * fp1;
}

__device__ __forceinline__ void step_fwd_lin(float a[8], const float g[4]) {
  float an[8];
#pragma unroll
  for (int sn = 0; sn < 8; ++sn) {
    const int u0 = ((sn >> 2) ^ (sn & 1)) & 1;
    const int p0 = ((sn >> 2) ^ ((sn >> 1) & 1)) & 1;
    an[sn] = a[(sn & 3) * 2] * g[u0 * 2 + p0]
           + a[(sn & 3) * 2 + 1] * g[(u0 ^ 1) * 2 + (p0 ^ 1)];
  }
#pragma unroll
  for (int s = 0; s < 8; ++s) a[s] = an[s];
}

__device__ __forceinline__ void step_bwd_lin(float bt[8], const float g[4]) {
  float bn[8];
#pragma unroll
  for (int s = 0; s < 8; ++s) {
    const int s0 = s & 1, s1b = (s >> 1) & 1, s2b = (s >> 2) & 1;
    const int f0 = s1b ^ s0, q = s1b ^ s2b;
    bn[s] = g[q] * bt[(f0 << 2) | (s >> 1)]
          + g[2 + (q ^ 1)] * bt[((f0 ^ 1) << 2) | (s >> 1)];
  }
#pragma unroll
  for (int s = 0; s < 8; ++s) bt[s] = bn[s];
}

// max-renorm with tiny floor injection: NaN/underflow-proof
__device__ __forceinline__ void renorm_lin(float a[8]) {
  float m = fmaxf(fmaxf(fmaxf(a[0], a[1]), fmaxf(a[2], a[3])),
                  fmaxf(fmaxf(a[4], a[5]), fmaxf(a[6], a[7])));
  float r = RCPF(fmaxf(m, 1e-30f));
#pragma unroll
  for (int s = 0; s < 8; ++s) a[s] = fmaf(a[s], r, 1e-32f);
}

// ---- log8-packed boundary states: u8 = round(-16*log2(x)), clamp 255. ----
__device__ __forceinline__ unsigned long long pack8_log8(const float a[8]) {
  unsigned int us[8];
#pragma unroll
  for (int s = 0; s < 8; ++s) {
    float l = -16.0f * LOG2F(a[s]);
    l = fminf(l, 255.0f);
    us[s] = (unsigned int)(l + 0.5f);
  }
  unsigned int x = us[0] | (us[1] << 8) | (us[2] << 16) | (us[3] << 24);
  unsigned int y = us[4] | (us[5] << 8) | (us[6] << 16) | (us[7] << 24);
  return ((unsigned long long)y << 32) | x;
}

__device__ __forceinline__ void unpack8_log8(unsigned long long v, float a[8]) {
  unsigned int vx = (unsigned int)v, vy = (unsigned int)(v >> 32);
#pragma unroll
  for (int s = 0; s < 4; ++s)
    a[s] = EXP2F(-0.0625f * (float)((vx >> (8 * s)) & 0xFFu));
#pragma unroll
  for (int s = 0; s < 4; ++s)
    a[4 + s] = EXP2F(-0.0625f * (float)((vy >> (8 * s)) & 0xFFu));
}

// ---------------- workspace layout (shared host/device) -------------------
struct WSL {
  float* lpostT;
  float* gx1; float* gx2;              // fp32 extrinsic planes (exchanged)
  unsigned short* gy1; unsigned short* gy2;
  __half* ls1; __half* ls2;
  int* inv;
  unsigned int* bars;                  // custom-barrier slots (64B strided)
  unsigned long long *S1a, *S1b, *T1a, *T1b, *S2a, *S2b, *T2a, *T2b;
};

__host__ __device__ inline WSL ws_layout(char* ws) {
  const size_t KB = (size_t)K_ * B_;
  WSL w; char* p = ws;
  w.lpostT = (float*)p;            p += KB * 4;
  w.gx1    = (float*)p;            p += KB * 4;
  w.gx2    = (float*)p;            p += KB * 4;
  w.gy1    = (unsigned short*)p;   p += KB * 2;
  w.gy2    = (unsigned short*)p;   p += KB * 2;
  w.ls1    = (__half*)p;           p += KB * 2;
  w.ls2    = (__half*)p;           p += KB * 2;
  w.inv    = (int*)p;              p += (size_t)K_ * 4;
  w.bars   = (unsigned int*)p;     p += 4096;
  const size_t SB = (size_t)(C_ + 1) * B_;          // ull elements
  w.S1a = (unsigned long long*)p;  p += SB * 8;
  w.S1b = (unsigned long long*)p;  p += SB * 8;
  w.T1a = (unsigned long long*)p;  p += SB * 8;
  w.T1b = (unsigned long long*)p;  p += SB * 8;
  w.S2a = (unsigned long long*)p;  p += SB * 8;
  w.S2b = (unsigned long long*)p;  p += SB * 8;
  w.T2a = (unsigned long long*)p;  p += SB * 8;
  w.T2b = (unsigned long long*)p;  p += SB * 8;
  return w;                                          // ~48.3 MB total
}

// ---- fence-free grid barrier: leader atomicAdd + relaxed agent spin.
// No buffer_wbl2 / buffer_inv anywhere: producers' sc1 stores are already
// write-through (nothing dirty to flush), consumers' sc1 loads bypass L2
// (nothing stale to invalidate). __syncthreads() drains each wave's vmcnt
// before the arrive, which orders sc1 data stores ahead of the atomic.
__device__ __forceinline__ void dev_barrier(unsigned int* cnt,
                                            unsigned int nb) {
  __syncthreads();                       // all waves drain vm stores
  if (threadIdx.x == 0) {
    asm volatile("s_waitcnt vmcnt(0)" ::: "memory");
    __hip_atomic_fetch_add(cnt, 1u, __ATOMIC_RELAXED,
                           __HIP_MEMORY_SCOPE_AGENT);
    while (__hip_atomic_load(cnt, __ATOMIC_RELAXED,
                             __HIP_MEMORY_SCOPE_AGENT) < nb)
      __builtin_amdgcn_s_sleep(4);
  }
  __syncthreads();
}

// ---------------- one windowed BCJR half-iteration (linear domain) --------
// DEV=true: persistent-kernel phase; exchanged planes (gx, gxother, S/T)
// accessed with agent-scope sc1 ops. DEV=false: plain-launch fallback.
// Numerics identical to the proven kernel except gx planes are now fp32
// (extrinsic no longer rounded through fp16 -> strictly closer to ref).
template <bool DEV>
__device__ __forceinline__ void half_body(
    const int c,
    const float* __restrict__ gx,
    const unsigned short* __restrict__ gy,
    const __half* __restrict__ lsloc,
    const int* __restrict__ map,
    float* __restrict__ gxother,
    float* __restrict__ lpost_out,
    const unsigned long long* __restrict__ Sread,
    unsigned long long* __restrict__ Swrite,
    const unsigned long long* __restrict__ Tread,
    unsigned long long* __restrict__ Twrite,
    int wmode, int mode, int wrS) {
  const int b = threadIdx.x;
  const int kv = c * L_;
  const int kend = kv + L_;

  // ---- issue ALL independent loads upfront ----
  float gvx[L_];
  unsigned short rgy[L_];
  __half hls[L_];
#pragma unroll
  for (int i = 0; i < L_; ++i) {
    size_t o = (size_t)(kv + i) * B_ + b;
    gvx[i] = DEV ? ld_dev_f32(gx + o) : gx[o];
    rgy[i] = gy[o];
  }
  if (mode == 0) {
#pragma unroll
    for (int i = 0; i < L_; ++i)
      hls[i] = lsloc[(size_t)(kv + i) * B_ + b];   // local rows, cached
  }
  int jmap[L_];
#pragma unroll
  for (int i = 0; i < L_; ++i) jmap[i] = map[kv + i];     // block-uniform
  unsigned long long sraw = 0, traw = 0;
  float wfx[W0_], wbx[W0_];
  unsigned short wfy[W0_], wby[W0_];
  if (wmode == 2) {
    if (c > 0) {
      const size_t o = (size_t)c * B_ + b;
      sraw = DEV ? ld_dev_u64(Sread + o) : Sread[o];
    }
    if (c < C_ - 1) {
      const size_t o = (size_t)(c + 1) * B_ + b;
      traw = DEV ? ld_dev_u64(Tread + o) : Tread[o];
    }
  } else {
    // warmup gammas, all upfront (wu == W0_ exactly, since kv >= W0_ at c>=1)
    if (c > 0) {
#pragma unroll
      for (int q = 0; q < W0_; ++q) {
        size_t o = (size_t)(kv - W0_ + q) * B_ + b;
        wfx[q] = DEV ? ld_dev_f32(gx + o) : gx[o];
        wfy[q] = gy[o];
      }
    }
    if (c < C_ - 1) {
#pragma unroll
      for (int q = 0; q < W0_; ++q) {
        size_t o = (size_t)(kend + W0_ - 1 - q) * B_ + b;
        wbx[q] = DEV ? ld_dev_f32(gx + o) : gx[o];
        wby[q] = gy[o];
      }
    }
  }

  // ---- valid gammas (gvx kept: needed for extrinsic) ----
  float gc[L_][4];
#pragma unroll
  for (int i = 0; i < L_; ++i) gam_lin(gvx[i], b2f(rgy[i]), gc[i]);

  // ---------------- forward ----------------
  float a[8];
  if (c == 0) {
    a[0] = 1.0f;
#pragma unroll
    for (int s = 1; s < 8; ++s) a[s] = 0.0f;
  } else if (wmode == 0) {
    if (c == 1) {                    // warmup starts at position 0: exact init
      a[0] = 1.0f;
#pragma unroll
      for (int s = 1; s < 8; ++s) a[s] = 0.0f;
    } else {
#pragma unroll
      for (int s = 0; s < 8; ++s) a[s] = 1.0f;
    }
#pragma unroll
    for (int q = 0; q < W0_; ++q) {
      float g[4];
      gam_lin(wfx[q], b2f(wfy[q]), g);
      step_fwd_lin(a, g);
      if (q & 1) renorm_lin(a);
    }
  } else {
    unpack8_log8(sraw, a);           // pure inheritance (c>0 here)
  }
  // valid region: record alpha, then step (all L steps -> a = alpha(kend))
  float a2d[L_][8];
#pragma unroll
  for (int i = 0; i < L_; ++i) {
#pragma unroll
    for (int s = 0; s < 8; ++s) a2d[i][s] = a[s];
    step_fwd_lin(a, gc[i]);
    if (i & 1) renorm_lin(a);
  }
  if (wrS) {
    unsigned long long v = pack8_log8(a);
    unsigned long long* p = Swrite + (size_t)(c + 1) * B_ + b;
    if (DEV) st_dev_u64(p, v); else *p = v;
  }

  // ---------------- backward + posterior ----------------
  float bt[8];
  if (c == C_ - 1) {
#pragma unroll
    for (int s = 0; s < 8; ++s) bt[s] = 1.0f;    // exact tail init (uniform)
  } else if (wmode == 0) {
#pragma unroll
    for (int s = 0; s < 8; ++s) bt[s] = 1.0f;    // uniform (exact at c=C_-2)
#pragma unroll
    for (int q = 0; q < W0_; ++q) {
      float g[4];
      gam_lin(wbx[q], b2f(wby[q]), g);
      step_bwd_lin(bt, g);
      if (q & 1) renorm_lin(bt);
    }
  } else {
    unpack8_log8(traw, bt);          // pure inheritance (c<C_-1 here)
  }
  // valid region, descending: posterior + extrinsic + beta step
#pragma unroll
  for (int ii = 0; ii < L_; ++ii) {
    const int i = L_ - 1 - ii;
    const float* g = gc[i];
    float s00 = 0.0f, s01 = 0.0f, s10 = 0.0f, s11 = 0.0f;
    float bn[8];
#pragma unroll
    for (int s = 0; s < 8; ++s) {
      const int s0 = s & 1, s1b = (s >> 1) & 1, s2b = (s >> 2) & 1;
      const int f0 = s1b ^ s0, q = s1b ^ s2b;
      float b0 = bt[(f0 << 2) | (s >> 1)];
      float b1 = bt[((f0 ^ 1) << 2) | (s >> 1)];
      float m0 = a2d[i][s] * b0;
      float m1 = a2d[i][s] * b1;
      if (q == 0) { s00 += m0; s10 += m1; } else { s01 += m0; s11 += m1; }
      bn[s] = g[q] * b0 + g[2 + (q ^ 1)] * b1;
    }
    float t0 = g[0] * s00 + g[1] * s01;
    float t1 = g[3] * s10 + g[2] * s11;
    float lpost = LOG2F(fmaxf(t0, 1e-37f)) - LOG2F(fmaxf(t1, 1e-37f));
    const size_t oo = (size_t)jmap[i] * B_ + b;
    if (mode == 0) {
      float le = lpost - gvx[i];                 // lpost - (ls + la)
      float v = __half2float(hls[i]) + le;
      if (DEV) st_dev_f32(gxother + oo, v); else gxother[oo] = v;
    } else {
      lpost_out[oo] = -LN2 * lpost;              // final value, row perm[kk]
    }
#pragma unroll
    for (int s = 0; s < 8; ++s) bt[s] = bn[s];
    if (ii & 1) renorm_lin(bt);
  }
  if (wrS) {
    unsigned long long v = pack8_log8(bt);
    unsigned long long* p = Twrite + (size_t)c * B_ + b;
    if (DEV) st_dev_u64(p, v); else *p = v;
  }
}

// ---------------- persistent cooperative megakernel -----------------------
// Custom fence-free barriers; only the exchanged planes use sc1 ops, so gy/
// ls/inv/perm stay L2-resident across all 12 phases (the round-2 failure was
// grid.sync's full L2 wb+inv costing ~45 MB refetch per barrier).
__global__ __launch_bounds__(256, 4) void k_fused(const int* __restrict__ perm,
                                                  char* __restrict__ ws) {
  WSL w = ws_layout(ws);
  const int tid = threadIdx.x;

  // prologue: ls2 gather. Rows c*L..c*L+5 are written and later read by the
  // SAME block (grid-stride mapping identical in every phase) -> plain
  // cached stores, no barrier needed.
  for (int c = blockIdx.x; c < C_; c += gridDim.x) {
#pragma unroll
    for (int r = 0; r < L_; ++r) {
      const int j = c * L_ + r;
      w.ls2[(size_t)j * B_ + tid] = w.ls1[(size_t)perm[j] * B_ + tid];
    }
  }

  int slot = 0;
  for (int it = 0; it < NITER; ++it) {
    const int pr = it & 1;
    const int wm = (it == 0) ? 0 : 2;
    const int wrS = (it != NITER - 1) ? 1 : 0;
    unsigned long long* S1r = pr ? w.S1b : w.S1a;
    unsigned long long* S1w = pr ? w.S1a : w.S1b;
    unsigned long long* T1r = pr ? w.T1b : w.T1a;
    unsigned long long* T1w = pr ? w.T1a : w.T1b;
    unsigned long long* S2r = pr ? w.S2b : w.S2a;
    unsigned long long* S2w = pr ? w.S2a : w.S2b;
    unsigned long long* T2r = pr ? w.T2b : w.T2a;
    unsigned long long* T2w = pr ? w.T2a : w.T2b;
    // phase 0 (decoder 1): extrinsic -> gx2[inv[kk]]; local ls plane = ls1.
    // gx1 holds prep1's fp32 ls values at it0 (la=0), so no special case.
    for (int c = blockIdx.x; c < C_; c += gridDim.x)
      half_body<true>(c, w.gx1, w.gy1, w.ls1, w.inv, w.gx2, w.lpostT,
                      S1r, S1w, T1r, T1w, wm, 0, wrS);
    dev_barrier(&w.bars[slot * 16], gridDim.x); ++slot;
    // phase 1 (decoder 2): extrinsic -> gx1[perm[kk]]; local ls plane = ls2
    for (int c = blockIdx.x; c < C_; c += gridDim.x)
      half_body<true>(c, w.gx2, w.gy2, w.ls2, perm, w.gx1, w.lpostT,
                      S2r, S2w, T2r, T2w, wm, (it == NITER - 1) ? 1 : 0, wrS);
    if (it != NITER - 1) { dev_barrier(&w.bars[slot * 16], gridDim.x); ++slot; }
  }
  // lpostT written with plain stores; kernel-end implicit release flushes it
  // for the separate k_out dispatch.
}

// ---------------- fallback kernels (proven multi-launch path) -------------
__global__ __launch_bounds__(256, 4) void k_half(
    const float* __restrict__ gx, const unsigned short* __restrict__ gy,
    const __half* __restrict__ lsloc, const int* __restrict__ map,
    float* __restrict__ gxother, float* __restrict__ lpost_out,
    const unsigned long long* __restrict__ Sread,
    unsigned long long* __restrict__ Swrite,
    const unsigned long long* __restrict__ Tread,
    unsigned long long* __restrict__ Twrite,
    int wmode, int mode, int wrS) {
  half_body<false>(blockIdx.x, gx, gy, lsloc, map, gxother, lpost_out,
                   Sread, Swrite, Tread, Twrite, wmode, mode, wrS);
}

__global__ __launch_bounds__(256) void k_prep2(const __half* __restrict__ ls1,
                                               const int* __restrict__ perm,
                                               __half* __restrict__ ls2) {
  const int b = threadIdx.x;
#pragma unroll
  for (int r = 0; r < 8; ++r) {
    const int j = blockIdx.x * 8 + r;
    ls2[(size_t)j * B_ + b] = ls1[(size_t)perm[j] * B_ + b];
  }
}

__global__ __launch_bounds__(256) void k_out(const float* __restrict__ lpostT,
                                             float* __restrict__ out) {
  __shared__ float t[64][65];
  const int tid = threadIdx.x;
  const int i0 = blockIdx.x * 64, b0 = blockIdx.y * 64;
  const int tb = tid & 63, iq = tid >> 6;
  for (int ii = iq; ii < 64; ii += 4) {
    t[ii][tb] = lpostT[(size_t)(i0 + ii) * B_ + (b0 + tb)];
  }
  __syncthreads();
  const int ik = tid & 63, bq = tid >> 6;
  for (int bb = bq; bb < 64; bb += 4) {
    out[(size_t)(b0 + bb) * K_ + (i0 + ik)] = t[ik][bb];
  }
}

// ---------------- prep: de-interleave + transpose + scale to log2 domain --
// Also: writes fp32 ls values into gx1 (the it0 phase-0 gamma plane, la=0),
// computes inv, and zeroes the barrier slots (kernel-end flush makes all of
// it visible to the cooperative kernel).
__global__ __launch_bounds__(256) void k_prep1(const float* __restrict__ inp,
                                               const int* __restrict__ perm,
                                               float* __restrict__ gx1,
                                               __half* __restrict__ ls1,
                                               unsigned short* __restrict__ gy1,
                                               unsigned short* __restrict__ gy2,
                                               int* __restrict__ inv,
                                               unsigned int* __restrict__ bars) {
  __shared__ float t[3][64][65];
  const int tid = threadIdx.x;
  const int k0 = blockIdx.x * 64, b0 = blockIdx.y * 64;
  const int tk = tid & 63, tq = tid >> 6;
  for (int bb = tq; bb < 64; bb += 4) {
    size_t base = (size_t)(b0 + bb) * (3 * K_) + 3 * (size_t)(k0 + tk);
    t[0][bb][tk] = inp[base + 0];
    t[1][bb][tk] = inp[base + 1];
    t[2][bb][tk] = inp[base + 2];
  }
  __syncthreads();
  const int tb = tid & 63, kq = tid >> 6;
  for (int kk = kq; kk < 64; kk += 4) {
    size_t o = (size_t)(k0 + kk) * B_ + (b0 + tb);
    float sv = -LOG2E * t[0][tb][kk];
    float p1 = -LOG2E * t[1][tb][kk];
    float p2 = -LOG2E * t[2][tb][kk];
    gx1[o] = sv;
    ls1[o] = __float2half(sv);
    gy1[o] = f2b(p1);
    gy2[o] = f2b(p2);
  }
  if (blockIdx.y == 0 && tid < 64) {
    const int j = k0 + tid;
    inv[perm[j]] = j;
  }
  if (blockIdx.x == 0 && blockIdx.y == 0) bars[tid] = 0;  // 256 uints >= slots
}

// ---------------- launch ---------------------------------------------------
static void launch_fallback(const int* perm, float* out, char* wsb,
                            hipStream_t stream) {
  WSL w = ws_layout(wsb);
  k_prep2<<<K_ / 8, 256, 0, stream>>>(w.ls1, perm, w.ls2);
  for (int it = 0; it < NITER; ++it) {
    const int pr = it & 1;
    const int wm = (it == 0) ? 0 : 2;
    const int wrS = (it != NITER - 1) ? 1 : 0;
    unsigned long long* S1r = pr ? w.S1b : w.S1a;
    unsigned long long* S1w = pr ? w.S1a : w.S1b;
    unsigned long long* T1r = pr ? w.T1b : w.T1a;
    unsigned long long* T1w = pr ? w.T1a : w.T1b;
    unsigned long long* S2r = pr ? w.S2b : w.S2a;
    unsigned long long* S2w = pr ? w.S2a : w.S2b;
    unsigned long long* T2r = pr ? w.T2b : w.T2a;
    unsigned long long* T2w = pr ? w.T2a : w.T2b;
    k_half<<<C_, 256, 0, stream>>>(w.gx1, w.gy1, w.ls1, w.inv, w.gx2,
                                   w.lpostT, S1r, S1w, T1r, T1w, wm, 0, wrS);
    k_half<<<C_, 256, 0, stream>>>(w.gx2, w.gy2, w.ls2, perm, w.gx1,
                                   w.lpostT, S2r, S2w, T2r, T2w, wm,
                                   (it == NITER - 1) ? 1 : 0, wrS);
  }
  k_out<<<dim3(K_ / 64, B_ / 64), 256, 0, stream>>>(w.lpostT, out);
}

extern "C" void kernel_launch(void* const* d_in, const int* in_sizes, int n_in,
                              void* d_out, int out_size, void* d_ws, size_t ws_size,
                              hipStream_t stream) {
  (void)in_sizes; (void)n_in; (void)out_size; (void)ws_size;
  const float* inp = (const float*)d_in[0];
  const int* perm = (const int*)d_in[1];
  float* out = (float*)d_out;
  char* wsb = (char*)d_ws;
  WSL w = ws_layout(wsb);

  k_prep1<<<dim3(K_ / 64, B_ / 64), 256, 0, stream>>>(
      inp, perm, w.gx1, w.ls1, w.gy1, w.gy2, w.inv, w.bars);

  // mode: 0 = undecided, 1 = cooperative megakernel, 2 = fallback launches.
  // Decided on the first non-capturing call (harness's eager correctness run
  // precedes graph capture) so a failing coop launch never lands in a capture.
  static int g_mode = 0;
  static int g_grid = 0;

  bool coop = false;
  if (g_mode == 0) {
    hipStreamCaptureStatus cap = hipStreamCaptureStatusNone;
    (void)hipStreamIsCapturing(stream, &cap);
    if (cap == hipStreamCaptureStatusNone) {
      int nb = 0;
      if (hipOccupancyMaxActiveBlocksPerMultiprocessor(&nb, k_fused, 256, 0)
              != hipSuccess)
        nb = 0;
      int ncu = 0;
      hipDeviceProp_t prop;
      int dev = 0;
      (void)hipGetDevice(&dev);
      if (hipGetDeviceProperties(&prop, dev) == hipSuccess)
        ncu = prop.multiProcessorCount;
      long long g = (long long)nb * (long long)ncu;
      int grid = (g > C_) ? C_ : (int)g;
      if (grid >= 8) {
        void* kargs[] = {(void*)&perm, (void*)&wsb};
        hipError_t e = hipLaunchCooperativeKernel((void*)k_fused, dim3(grid),
                                                  dim3(256), kargs, 0, stream);
        if (e == hipSuccess) {
          g_mode = 1; g_grid = grid; coop = true;
        } else {
          g_mode = 2;
        }
      } else {
        g_mode = 2;
      }
    }
  } else if (g_mode == 1) {
    void* kargs[] = {(void*)&perm, (void*)&wsb};
    (void)hipLaunchCooperativeKernel((void*)k_fused, dim3(g_grid), dim3(256),
                                     kargs, 0, stream);
    coop = true;
  }

  if (coop) {
    k_out<<<dim3(K_ / 64, B_ / 64), 256, 0, stream>>>(w.lpostT, out);
  } else {
    launch_fallback(perm, out, wsb, stream);
  }
}

// Round 4
// 262.573 us; speedup vs baseline: 7.6599x; 1.6049x over previous
//
#include <hip/hip_runtime.h>
#include <hip/hip_fp16.h>

// ---------------- problem constants ----------------
constexpr int B_ = 256;        // batch
constexpr int K_ = 6144;       // block length
constexpr int NITER = 6;
constexpr int L_ = 6;          // window valid length -> C_=1024 chunks
constexpr int W0_ = 6;         // uniform-init warmup (iteration 0)
constexpr int C_ = K_ / L_;    // chunks = 1024
constexpr float LOG2E = 1.4426950408889634f;
constexpr float LN2   = 0.6931471805599453f;

static_assert(K_ % L_ == 0, "");
static_assert((L_ % 2) == 0 && (W0_ % 2) == 0, "");
static_assert(W0_ <= L_, "uniform-warmup trick requires W0 <= L");

#if __has_builtin(__builtin_amdgcn_exp2f)
#define EXP2F(x) __builtin_amdgcn_exp2f(x)
#else
#define EXP2F(x) exp2f(x)
#endif
#if __has_builtin(__builtin_amdgcn_logf)
#define LOG2F(x) __builtin_amdgcn_logf(x)
#else
#define LOG2F(x) log2f(x)
#endif
#if __has_builtin(__builtin_amdgcn_rcpf)
#define RCPF(x) __builtin_amdgcn_rcpf(x)
#else
#define RCPF(x) (1.0f / (x))
#endif

// ---- bf16 scalar helpers (RNE) ----
__device__ __forceinline__ float b2f(unsigned short u) {
  return __uint_as_float((unsigned)u << 16);
}
__device__ __forceinline__ unsigned short f2b(float f) {
  unsigned u = __float_as_uint(f);
  u += 0x7FFFu + ((u >> 16) & 1u);
  return (unsigned short)(u >> 16);
}
// fp16 bit helpers
__device__ __forceinline__ float h2f_bits(unsigned short us) {
  __half_raw r; r.x = us; return __half2float(__half(r));
}
__device__ __forceinline__ unsigned short f2h_bits(float f) {
  return __half_as_ushort(__float2half(f));
}

// ---- agent-scope (cross-XCD) relaxed accessors: sc1 ops bypass the
// non-coherent per-XCD L2s and hit the device coherence point. Targeted
// use keeps read-only planes (gy/ls/inv/perm) L2-resident across phases.
__device__ __forceinline__ unsigned int ld_dev_u32(const unsigned int* p) {
  return __hip_atomic_load(const_cast<unsigned int*>(p), __ATOMIC_RELAXED,
                           __HIP_MEMORY_SCOPE_AGENT);
}
__device__ __forceinline__ void st_dev_u32(unsigned int* p, unsigned int v) {
  __hip_atomic_store(p, v, __ATOMIC_RELAXED, __HIP_MEMORY_SCOPE_AGENT);
}
__device__ __forceinline__ unsigned long long ld_dev_u64(
    const unsigned long long* p) {
  return __hip_atomic_load(const_cast<unsigned long long*>(p),
                           __ATOMIC_RELAXED, __HIP_MEMORY_SCOPE_AGENT);
}
__device__ __forceinline__ void st_dev_u64(unsigned long long* p,
                                           unsigned long long v) {
  __hip_atomic_store(p, v, __ATOMIC_RELAXED, __HIP_MEMORY_SCOPE_AGENT);
}

// trellis: fb(s,u)=u^s1^s0, nxt(s,u)=(fb<<2)|(s>>1), par(s,u)=u^s1^s2
__device__ __forceinline__ void gam_lin(float gxv, float gyv, float g[4]) {
  float es = EXP2F(-fabsf(gxv));
  float ep = EXP2F(-fabsf(gyv));
  float fu0 = gxv >= 0.0f ? 1.0f : es;
  float fu1 = gxv >= 0.0f ? es : 1.0f;
  float fp0 = gyv >= 0.0f ? 1.0f : ep;
  float fp1 = gyv >= 0.0f ? ep : 1.0f;
  g[0] = fu0 * fp0; g[1] = fu0 * fp1;
  g[2] = fu1 * fp0; g[3] = fu1 * fp1;
}

__device__ __forceinline__ void step_fwd_lin(float a[8], const float g[4]) {
  float an[8];
#pragma unroll
  for (int sn = 0; sn < 8; ++sn) {
    const int u0 = ((sn >> 2) ^ (sn & 1)) & 1;
    const int p0 = ((sn >> 2) ^ ((sn >> 1) & 1)) & 1;
    an[sn] = a[(sn & 3) * 2] * g[u0 * 2 + p0]
           + a[(sn & 3) * 2 + 1] * g[(u0 ^ 1) * 2 + (p0 ^ 1)];
  }
#pragma unroll
  for (int s = 0; s < 8; ++s) a[s] = an[s];
}

__device__ __forceinline__ void step_bwd_lin(float bt[8], const float g[4]) {
  float bn[8];
#pragma unroll
  for (int s = 0; s < 8; ++s) {
    const int s0 = s & 1, s1b = (s >> 1) & 1, s2b = (s >> 2) & 1;
    const int f0 = s1b ^ s0, q = s1b ^ s2b;
    bn[s] = g[q] * bt[(f0 << 2) | (s >> 1)]
          + g[2 + (q ^ 1)] * bt[((f0 ^ 1) << 2) | (s >> 1)];
  }
#pragma unroll
  for (int s = 0; s < 8; ++s) bt[s] = bn[s];
}

// max-renorm with tiny floor injection: NaN/underflow-proof
__device__ __forceinline__ void renorm_lin(float a[8]) {
  float m = fmaxf(fmaxf(fmaxf(a[0], a[1]), fmaxf(a[2], a[3])),
                  fmaxf(fmaxf(a[4], a[5]), fmaxf(a[6], a[7])));
  float r = RCPF(fmaxf(m, 1e-30f));
#pragma unroll
  for (int s = 0; s < 8; ++s) a[s] = fmaf(a[s], r, 1e-32f);
}

// ---- log8-packed boundary states: u8 = round(-16*log2(x)), clamp 255. ----
__device__ __forceinline__ unsigned long long pack8_log8(const float a[8]) {
  unsigned int us[8];
#pragma unroll
  for (int s = 0; s < 8; ++s) {
    float l = -16.0f * LOG2F(a[s]);
    l = fminf(l, 255.0f);
    us[s] = (unsigned int)(l + 0.5f);
  }
  unsigned int x = us[0] | (us[1] << 8) | (us[2] << 16) | (us[3] << 24);
  unsigned int y = us[4] | (us[5] << 8) | (us[6] << 16) | (us[7] << 24);
  return ((unsigned long long)y << 32) | x;
}

__device__ __forceinline__ void unpack8_log8(unsigned long long v, float a[8]) {
  unsigned int vx = (unsigned int)v, vy = (unsigned int)(v >> 32);
#pragma unroll
  for (int s = 0; s < 4; ++s)
    a[s] = EXP2F(-0.0625f * (float)((vx >> (8 * s)) & 0xFFu));
#pragma unroll
  for (int s = 0; s < 4; ++s)
    a[4 + s] = EXP2F(-0.0625f * (float)((vy >> (8 * s)) & 0xFFu));
}

// ---------------- tree barrier geometry -----------------------------------
// Per slot: 32 group-counter lines + 32 release lines + 1 root line, each
// 128 B (32 uints). Arrive: leader RMWs its group line (max 32 serialized
// RMWs, parallel across lines); group-finisher RMWs root (32 RMWs); root-
// finisher stores all 32 release flags. Poll: ~32 leaders per release line,
// reads only. No line carries both RMW and poll traffic.
constexpr int NSLOT = 2 * NITER - 1;       // 11 barriers
constexpr int SLOT_U = 65 * 32;            // uints per slot
constexpr int BARS_U = 24576;              // alloc (>= NSLOT*SLOT_U = 22880)

__device__ __forceinline__ void tree_barrier(unsigned int* slotBase,
                                             unsigned int gsz) {
  __syncthreads();                         // waves drain vm before arrive
  if (threadIdx.x == 0) {
    const unsigned int g = blockIdx.x & 31u;
    unsigned int* cnt = slotBase + g * 32;
    unsigned int* rel = slotBase + (32 + g) * 32;
    unsigned int* root = slotBase + 64 * 32;
    asm volatile("s_waitcnt vmcnt(0)" ::: "memory");
    unsigned int m = __hip_atomic_fetch_add(cnt, 1u, __ATOMIC_RELAXED,
                                            __HIP_MEMORY_SCOPE_AGENT);
    if (m == gsz - 1u) {                   // last of group -> root
      unsigned int r = __hip_atomic_fetch_add(root, 1u, __ATOMIC_RELAXED,
                                              __HIP_MEMORY_SCOPE_AGENT);
      if (r == 31u) {                      // last group -> broadcast release
#pragma unroll
        for (int gg = 0; gg < 32; ++gg)
          st_dev_u32(slotBase + (32 + gg) * 32, 1u);
      }
    }
    while (!ld_dev_u32(rel))
      __builtin_amdgcn_s_sleep(2);
  }
  __syncthreads();
}

// ---------------- workspace layout (shared host/device) -------------------
struct WSL {
  float* lpostT;
  __half* gx1; __half* gx2;            // fp16 extrinsic planes, PAIR-PACKED:
                                       // u32 at [j*(B/2)+(b>>1)] = cols b,b+1
  unsigned short* gy1; unsigned short* gy2;
  __half* ls1; __half* ls2;
  int* inv;
  unsigned int* bars;
  unsigned long long *S1a, *S1b, *T1a, *T1b, *S2a, *S2b, *T2a, *T2b;
};

__host__ __device__ inline WSL ws_layout(char* ws) {
  const size_t KB = (size_t)K_ * B_;
  WSL w; char* p = ws;
  w.lpostT = (float*)p;            p += KB * 4;
  w.gx1    = (__half*)p;           p += KB * 2;
  w.gx2    = (__half*)p;           p += KB * 2;
  w.gy1    = (unsigned short*)p;   p += KB * 2;
  w.gy2    = (unsigned short*)p;   p += KB * 2;
  w.ls1    = (__half*)p;           p += KB * 2;
  w.ls2    = (__half*)p;           p += KB * 2;
  w.inv    = (int*)p;              p += (size_t)K_ * 4;
  w.bars   = (unsigned int*)p;     p += (size_t)BARS_U * 4;
  const size_t SB = (size_t)(C_ + 1) * B_;          // ull elements
  w.S1a = (unsigned long long*)p;  p += SB * 8;
  w.S1b = (unsigned long long*)p;  p += SB * 8;
  w.T1a = (unsigned long long*)p;  p += SB * 8;
  w.T1b = (unsigned long long*)p;  p += SB * 8;
  w.S2a = (unsigned long long*)p;  p += SB * 8;
  w.S2b = (unsigned long long*)p;  p += SB * 8;
  w.T2a = (unsigned long long*)p;  p += SB * 8;
  w.T2b = (unsigned long long*)p;  p += SB * 8;
  return w;                                          // ~42.2 MB total
}

// ---------------- one windowed BCJR half-iteration (linear domain) --------
// DEV=true: persistent-kernel phase; exchanged planes (gx, gxother, S/T) use
// agent-scope sc1 ops. DEV=false: plain-launch fallback. gx planes are fp16
// pair-packed u32 -> numerics are bit-identical to the proven baseline
// (extrinsic rounded through fp16).
template <bool DEV>
__device__ __forceinline__ void half_body(
    const int c,
    const __half* __restrict__ gx,
    const unsigned short* __restrict__ gy,
    const __half* __restrict__ lsloc,
    const int* __restrict__ map,
    __half* __restrict__ gxother,
    float* __restrict__ lpost_out,
    const unsigned long long* __restrict__ Sread,
    unsigned long long* __restrict__ Swrite,
    const unsigned long long* __restrict__ Tread,
    unsigned long long* __restrict__ Twrite,
    int wmode, int mode, int wrS) {
  const int b = threadIdx.x;
  const int kv = c * L_;
  const int kend = kv + L_;
  const unsigned int* gxp = (const unsigned int*)gx;   // packed [K][B/2]
  const int bh = b >> 1;
  const unsigned int hsel = (b & 1) * 16;              // shift for my half

  // ---- issue ALL independent loads upfront ----
  float gvx[L_];
  unsigned short rgy[L_];
  __half hls[L_];
#pragma unroll
  for (int i = 0; i < L_; ++i) {
    size_t o2 = (size_t)(kv + i) * (B_ / 2) + bh;
    unsigned int u = DEV ? ld_dev_u32(gxp + o2) : gxp[o2];
    gvx[i] = h2f_bits((unsigned short)(u >> hsel));
    rgy[i] = gy[(size_t)(kv + i) * B_ + b];
  }
  if (mode == 0) {
#pragma unroll
    for (int i = 0; i < L_; ++i)
      hls[i] = lsloc[(size_t)(kv + i) * B_ + b];   // local rows, cached
  }
  int jmap[L_];
#pragma unroll
  for (int i = 0; i < L_; ++i) jmap[i] = map[kv + i];     // block-uniform
  unsigned long long sraw = 0, traw = 0;
  float wfx[W0_], wbx[W0_];
  unsigned short wfy[W0_], wby[W0_];
  if (wmode == 2) {
    if (c > 0) {
      const size_t o = (size_t)c * B_ + b;
      sraw = DEV ? ld_dev_u64(Sread + o) : Sread[o];
    }
    if (c < C_ - 1) {
      const size_t o = (size_t)(c + 1) * B_ + b;
      traw = DEV ? ld_dev_u64(Tread + o) : Tread[o];
    }
  } else {
    // warmup gammas, all upfront (wu == W0_ exactly, since kv >= W0_ at c>=1)
    if (c > 0) {
#pragma unroll
      for (int q = 0; q < W0_; ++q) {
        size_t o2 = (size_t)(kv - W0_ + q) * (B_ / 2) + bh;
        unsigned int u = DEV ? ld_dev_u32(gxp + o2) : gxp[o2];
        wfx[q] = h2f_bits((unsigned short)(u >> hsel));
        wfy[q] = gy[(size_t)(kv - W0_ + q) * B_ + b];
      }
    }
    if (c < C_ - 1) {
#pragma unroll
      for (int q = 0; q < W0_; ++q) {
        size_t o2 = (size_t)(kend + W0_ - 1 - q) * (B_ / 2) + bh;
        unsigned int u = DEV ? ld_dev_u32(gxp + o2) : gxp[o2];
        wbx[q] = h2f_bits((unsigned short)(u >> hsel));
        wby[q] = gy[(size_t)(kend + W0_ - 1 - q) * B_ + b];
      }
    }
  }

  // ---- valid gammas (gvx kept: needed for extrinsic) ----
  float gc[L_][4];
#pragma unroll
  for (int i = 0; i < L_; ++i) gam_lin(gvx[i], b2f(rgy[i]), gc[i]);

  // ---------------- forward ----------------
  float a[8];
  if (c == 0) {
    a[0] = 1.0f;
#pragma unroll
    for (int s = 1; s < 8; ++s) a[s] = 0.0f;
  } else if (wmode == 0) {
    if (c == 1) {                    // warmup starts at position 0: exact init
      a[0] = 1.0f;
#pragma unroll
      for (int s = 1; s < 8; ++s) a[s] = 0.0f;
    } else {
#pragma unroll
      for (int s = 0; s < 8; ++s) a[s] = 1.0f;
    }
#pragma unroll
    for (int q = 0; q < W0_; ++q) {
      float g[4];
      gam_lin(wfx[q], b2f(wfy[q]), g);
      step_fwd_lin(a, g);
      if (q & 1) renorm_lin(a);
    }
  } else {
    unpack8_log8(sraw, a);           // pure inheritance (c>0 here)
  }
  // valid region: record alpha, then step (all L steps -> a = alpha(kend))
  float a2d[L_][8];
#pragma unroll
  for (int i = 0; i < L_; ++i) {
#pragma unroll
    for (int s = 0; s < 8; ++s) a2d[i][s] = a[s];
    step_fwd_lin(a, gc[i]);
    if (i & 1) renorm_lin(a);
  }
  if (wrS) {
    unsigned long long v = pack8_log8(a);
    unsigned long long* p = Swrite + (size_t)(c + 1) * B_ + b;
    if (DEV) st_dev_u64(p, v); else *p = v;
  }

  // ---------------- backward + posterior ----------------
  float bt[8];
  if (c == C_ - 1) {
#pragma unroll
    for (int s = 0; s < 8; ++s) bt[s] = 1.0f;    // exact tail init (uniform)
  } else if (wmode == 0) {
#pragma unroll
    for (int s = 0; s < 8; ++s) bt[s] = 1.0f;    // uniform (exact at c=C_-2)
#pragma unroll
    for (int q = 0; q < W0_; ++q) {
      float g[4];
      gam_lin(wbx[q], b2f(wby[q]), g);
      step_bwd_lin(bt, g);
      if (q & 1) renorm_lin(bt);
    }
  } else {
    unpack8_log8(traw, bt);          // pure inheritance (c<C_-1 here)
  }
  // valid region, descending: posterior + extrinsic + beta step
#pragma unroll
  for (int ii = 0; ii < L_; ++ii) {
    const int i = L_ - 1 - ii;
    const float* g = gc[i];
    float s00 = 0.0f, s01 = 0.0f, s10 = 0.0f, s11 = 0.0f;
    float bn[8];
#pragma unroll
    for (int s = 0; s < 8; ++s) {
      const int s0 = s & 1, s1b = (s >> 1) & 1, s2b = (s >> 2) & 1;
      const int f0 = s1b ^ s0, q = s1b ^ s2b;
      float b0 = bt[(f0 << 2) | (s >> 1)];
      float b1 = bt[((f0 ^ 1) << 2) | (s >> 1)];
      float m0 = a2d[i][s] * b0;
      float m1 = a2d[i][s] * b1;
      if (q == 0) { s00 += m0; s10 += m1; } else { s01 += m0; s11 += m1; }
      bn[s] = g[q] * b0 + g[2 + (q ^ 1)] * b1;
    }
    float t0 = g[0] * s00 + g[1] * s01;
    float t1 = g[3] * s10 + g[2] * s11;
    float lpost = LOG2F(fmaxf(t0, 1e-37f)) - LOG2F(fmaxf(t1, 1e-37f));
    if (mode == 0) {
      float le = lpost - gvx[i];                 // lpost - (ls + la)
      unsigned short us = f2h_bits(__half2float(hls[i]) + le);
      // pair-pack with lane partner (jmap row is uniform across lanes)
      unsigned int po = (unsigned int)__shfl_xor((int)us, 1);
      if (!(b & 1)) {
        unsigned int u = (unsigned int)us | (po << 16);
        unsigned int* p =
            (unsigned int*)gxother + ((size_t)jmap[i] * (B_ / 2) + bh);
        if (DEV) st_dev_u32(p, u); else *p = u;
      }
    } else {
      lpost_out[(size_t)jmap[i] * B_ + b] = -LN2 * lpost;  // final value
    }
#pragma unroll
    for (int s = 0; s < 8; ++s) bt[s] = bn[s];
    if (ii & 1) renorm_lin(bt);
  }
  if (wrS) {
    unsigned long long v = pack8_log8(bt);
    unsigned long long* p = Twrite + (size_t)c * B_ + b;
    if (DEV) st_dev_u64(p, v); else *p = v;
  }
}

// ---------------- persistent cooperative megakernel -----------------------
__global__ __launch_bounds__(256, 4) void k_fused(const int* __restrict__ perm,
                                                  char* __restrict__ ws) {
  WSL w = ws_layout(ws);
  const int tid = threadIdx.x;
  const unsigned int gsz = gridDim.x >> 5;   // blocks per barrier group

  // prologue: ls2 gather. Rows c*L..c*L+5 are written and later read by the
  // SAME block (grid-stride mapping identical in every phase) -> plain
  // cached stores, no barrier needed.
  for (int c = blockIdx.x; c < C_; c += gridDim.x) {
#pragma unroll
    for (int r = 0; r < L_; ++r) {
      const int j = c * L_ + r;
      w.ls2[(size_t)j * B_ + tid] = w.ls1[(size_t)perm[j] * B_ + tid];
    }
  }

  int slot = 0;
  for (int it = 0; it < NITER; ++it) {
    const int pr = it & 1;
    const int wm = (it == 0) ? 0 : 2;
    const int wrS = (it != NITER - 1) ? 1 : 0;
    unsigned long long* S1r = pr ? w.S1b : w.S1a;
    unsigned long long* S1w = pr ? w.S1a : w.S1b;
    unsigned long long* T1r = pr ? w.T1b : w.T1a;
    unsigned long long* T1w = pr ? w.T1a : w.T1b;
    unsigned long long* S2r = pr ? w.S2b : w.S2a;
    unsigned long long* S2w = pr ? w.S2a : w.S2b;
    unsigned long long* T2r = pr ? w.T2b : w.T2a;
    unsigned long long* T2w = pr ? w.T2a : w.T2b;
    // phase 0 (decoder 1): extrinsic -> gx2[inv[kk]]; local ls plane = ls1.
    // gx1 holds prep1's packed fp16 ls values at it0 (la=0).
    for (int c = blockIdx.x; c < C_; c += gridDim.x)
      half_body<true>(c, w.gx1, w.gy1, w.ls1, w.inv, w.gx2, w.lpostT,
                      S1r, S1w, T1r, T1w, wm, 0, wrS);
    tree_barrier(w.bars + slot * SLOT_U, gsz); ++slot;
    // phase 1 (decoder 2): extrinsic -> gx1[perm[kk]]; local ls plane = ls2
    for (int c = blockIdx.x; c < C_; c += gridDim.x)
      half_body<true>(c, w.gx2, w.gy2, w.ls2, perm, w.gx1, w.lpostT,
                      S2r, S2w, T2r, T2w, wm, (it == NITER - 1) ? 1 : 0, wrS);
    if (it != NITER - 1) { tree_barrier(w.bars + slot * SLOT_U, gsz); ++slot; }
  }
  // lpostT written with plain stores; kernel-end implicit release flushes it
  // for the separate k_out dispatch.
}

// ---------------- fallback kernels (proven multi-launch path) -------------
__global__ __launch_bounds__(256, 4) void k_half(
    const __half* __restrict__ gx, const unsigned short* __restrict__ gy,
    const __half* __restrict__ lsloc, const int* __restrict__ map,
    __half* __restrict__ gxother, float* __restrict__ lpost_out,
    const unsigned long long* __restrict__ Sread,
    unsigned long long* __restrict__ Swrite,
    const unsigned long long* __restrict__ Tread,
    unsigned long long* __restrict__ Twrite,
    int wmode, int mode, int wrS) {
  half_body<false>(blockIdx.x, gx, gy, lsloc, map, gxother, lpost_out,
                   Sread, Swrite, Tread, Twrite, wmode, mode, wrS);
}

__global__ __launch_bounds__(256) void k_prep2(const __half* __restrict__ ls1,
                                               const int* __restrict__ perm,
                                               __half* __restrict__ ls2) {
  const int b = threadIdx.x;
#pragma unroll
  for (int r = 0; r < 8; ++r) {
    const int j = blockIdx.x * 8 + r;
    ls2[(size_t)j * B_ + b] = ls1[(size_t)perm[j] * B_ + b];
  }
}

__global__ __launch_bounds__(256) void k_out(const float* __restrict__ lpostT,
                                             float* __restrict__ out) {
  __shared__ float t[64][65];
  const int tid = threadIdx.x;
  const int i0 = blockIdx.x * 64, b0 = blockIdx.y * 64;
  const int tb = tid & 63, iq = tid >> 6;
  for (int ii = iq; ii < 64; ii += 4) {
    t[ii][tb] = lpostT[(size_t)(i0 + ii) * B_ + (b0 + tb)];
  }
  __syncthreads();
  const int ik = tid & 63, bq = tid >> 6;
  for (int bb = bq; bb < 64; bb += 4) {
    out[(size_t)(b0 + bb) * K_ + (i0 + ik)] = t[ik][bb];
  }
}

// ---------------- prep: de-interleave + transpose + scale to log2 domain --
// Also: writes pair-packed fp16 ls into gx1 (it0 phase-0 gamma plane, la=0),
// computes inv, and zeroes the barrier region (kernel-end flush publishes
// everything for the cooperative kernel).
__global__ __launch_bounds__(256) void k_prep1(const float* __restrict__ inp,
                                               const int* __restrict__ perm,
                                               __half* __restrict__ gx1,
                                               __half* __restrict__ ls1,
                                               unsigned short* __restrict__ gy1,
                                               unsigned short* __restrict__ gy2,
                                               int* __restrict__ inv,
                                               unsigned int* __restrict__ bars) {
  __shared__ float t[3][64][65];
  const int tid = threadIdx.x;
  const int k0 = blockIdx.x * 64, b0 = blockIdx.y * 64;
  const int tk = tid & 63, tq = tid >> 6;
  for (int bb = tq; bb < 64; bb += 4) {
    size_t base = (size_t)(b0 + bb) * (3 * K_) + 3 * (size_t)(k0 + tk);
    t[0][bb][tk] = inp[base + 0];
    t[1][bb][tk] = inp[base + 1];
    t[2][bb][tk] = inp[base + 2];
  }
  __syncthreads();
  const int tb = tid & 63, kq = tid >> 6;
  for (int kk = kq; kk < 64; kk += 4) {
    size_t o = (size_t)(k0 + kk) * B_ + (b0 + tb);
    float sv = -LOG2E * t[0][tb][kk];
    float p1 = -LOG2E * t[1][tb][kk];
    float p2 = -LOG2E * t[2][tb][kk];
    ls1[o] = __float2half(sv);
    gy1[o] = f2b(p1);
    gy2[o] = f2b(p2);
    if (!(tb & 1)) {                      // pair-packed gx1 (cols tb, tb+1)
      float sv1 = -LOG2E * t[0][tb + 1][kk];
      unsigned int u = (unsigned int)f2h_bits(sv) |
                       ((unsigned int)f2h_bits(sv1) << 16);
      ((unsigned int*)gx1)[o >> 1] = u;
    }
  }
  if (blockIdx.y == 0 && tid < 64) {
    const int j = k0 + tid;
    inv[perm[j]] = j;
  }
  if (blockIdx.y == 1 && blockIdx.x < BARS_U / 1024) {   // zero barrier region
#pragma unroll
    for (int r = 0; r < 4; ++r)
      bars[(size_t)blockIdx.x * 1024 + r * 256 + tid] = 0;
  }
}

// ---------------- launch ---------------------------------------------------
static void launch_fallback(const int* perm, float* out, char* wsb,
                            hipStream_t stream) {
  WSL w = ws_layout(wsb);
  k_prep2<<<K_ / 8, 256, 0, stream>>>(w.ls1, perm, w.ls2);
  for (int it = 0; it < NITER; ++it) {
    const int pr = it & 1;
    const int wm = (it == 0) ? 0 : 2;
    const int wrS = (it != NITER - 1) ? 1 : 0;
    unsigned long long* S1r = pr ? w.S1b : w.S1a;
    unsigned long long* S1w = pr ? w.S1a : w.S1b;
    unsigned long long* T1r = pr ? w.T1b : w.T1a;
    unsigned long long* T1w = pr ? w.T1a : w.T1b;
    unsigned long long* S2r = pr ? w.S2b : w.S2a;
    unsigned long long* S2w = pr ? w.S2a : w.S2b;
    unsigned long long* T2r = pr ? w.T2b : w.T2a;
    unsigned long long* T2w = pr ? w.T2a : w.T2b;
    k_half<<<C_, 256, 0, stream>>>(w.gx1, w.gy1, w.ls1, w.inv, w.gx2,
                                   w.lpostT, S1r, S1w, T1r, T1w, wm, 0, wrS);
    k_half<<<C_, 256, 0, stream>>>(w.gx2, w.gy2, w.ls2, perm, w.gx1,
                                   w.lpostT, S2r, S2w, T2r, T2w, wm,
                                   (it == NITER - 1) ? 1 : 0, wrS);
  }
  k_out<<<dim3(K_ / 64, B_ / 64), 256, 0, stream>>>(w.lpostT, out);
}

extern "C" void kernel_launch(void* const* d_in, const int* in_sizes, int n_in,
                              void* d_out, int out_size, void* d_ws, size_t ws_size,
                              hipStream_t stream) {
  (void)in_sizes; (void)n_in; (void)out_size; (void)ws_size;
  const float* inp = (const float*)d_in[0];
  const int* perm = (const int*)d_in[1];
  float* out = (float*)d_out;
  char* wsb = (char*)d_ws;
  WSL w = ws_layout(wsb);

  k_prep1<<<dim3(K_ / 64, B_ / 64), 256, 0, stream>>>(
      inp, perm, w.gx1, w.ls1, w.gy1, w.gy2, w.inv, w.bars);

  // mode: 0 = undecided, 1 = cooperative megakernel, 2 = fallback launches.
  // Decided on the first non-capturing call (harness's eager correctness run
  // precedes graph capture) so a failing coop launch never lands in a capture.
  static int g_mode = 0;
  static int g_grid = 0;

  bool coop = false;
  if (g_mode == 0) {
    hipStreamCaptureStatus cap = hipStreamCaptureStatusNone;
    (void)hipStreamIsCapturing(stream, &cap);
    if (cap == hipStreamCaptureStatusNone) {
      int nb = 0;
      if (hipOccupancyMaxActiveBlocksPerMultiprocessor(&nb, k_fused, 256, 0)
              != hipSuccess)
        nb = 0;
      int ncu = 0;
      hipDeviceProp_t prop;
      int dev = 0;
      (void)hipGetDevice(&dev);
      if (hipGetDeviceProperties(&prop, dev) == hipSuccess)
        ncu = prop.multiProcessorCount;
      long long g = (long long)nb * (long long)ncu;
      int grid = (g > C_) ? C_ : (int)g;
      grid &= ~31;                        // tree barrier needs grid % 32 == 0
      if (grid >= 32) {
        void* kargs[] = {(void*)&perm, (void*)&wsb};
        hipError_t e = hipLaunchCooperativeKernel((void*)k_fused, dim3(grid),
                                                  dim3(256), kargs, 0, stream);
        if (e == hipSuccess) {
          g_mode = 1; g_grid = grid; coop = true;
        } else {
          g_mode = 2;
        }
      } else {
        g_mode = 2;
      }
    }
  } else if (g_mode == 1) {
    void* kargs[] = {(void*)&perm, (void*)&wsb};
    (void)hipLaunchCooperativeKernel((void*)k_fused, dim3(g_grid), dim3(256),
                                     kargs, 0, stream);
    coop = true;
  }

  if (coop) {
    k_out<<<dim3(K_ / 64, B_ / 64), 256, 0, stream>>>(w.lpostT, out);
  } else {
    launch_fallback(perm, out, wsb, stream);
  }
}